// Round 6
// baseline (503.186 us; speedup 1.0000x reference)
//
#include <hip/hip_runtime.h>
#include <hip/hip_bf16.h>

#define B_  64
#define T_  1024
#define H_  256
#define OUT_LEN_ 3072
#define TP_ 1056          // padded rows: 1 + 1024 + 31

typedef __attribute__((ext_vector_type(8))) short short8v;
typedef __attribute__((ext_vector_type(4))) float floatx4;

__device__ __forceinline__ unsigned short f2bf_rne(float f) {
    unsigned int u = __float_as_uint(f);
    u += 0x7FFFu + ((u >> 16) & 1u);
    return (unsigned short)(u >> 16);
}
__device__ __forceinline__ float bf2f(unsigned short h) {
    return __uint_as_float(((unsigned int)h) << 16);
}
__device__ __forceinline__ unsigned int packhl(float v) {
    unsigned short h = f2bf_rne(v);
    unsigned short l = f2bf_rne(v - bf2f(h));
    return (unsigned int)h | ((unsigned int)l << 16);
}
__device__ __forceinline__ void gload_lds16(const void* g, void* l) {
    __builtin_amdgcn_global_load_lds(
        (const __attribute__((address_space(1))) unsigned int*)g,
        (__attribute__((address_space(3))) unsigned int*)l, 16, 0, 0);
}

// ---------------------------------------------------------------------------
// w[O][I][3] -> limb layout (unchanged from R4/R5):
// idx = ((((c*2+arr)*3+tap)*4+grp)*256 + o)*8 + el,  ic = c*32+grp*8+el
// ---------------------------------------------------------------------------
__global__ __launch_bounds__(256) void convert_w_kernel(
    const float* __restrict__ w, unsigned short* __restrict__ wq)
{
    int e = blockIdx.x * 256 + threadIdx.x;
    if (e >= H_ * H_ * 3) return;
    int o = e / (H_ * 3);
    int rem = e - o * (H_ * 3);
    int ic = rem / 3;
    int tap = rem - ic * 3;
    float v = w[e];
    unsigned short h = f2bf_rne(v);
    unsigned short l = f2bf_rne(v - bf2f(h));
    int c = ic >> 5, grp = (ic >> 3) & 3, el = ic & 7;
    size_t hi_idx = ((((size_t)(c * 2 + 0) * 3 + tap) * 4 + grp) * 256 + o) * 8 + el;
    size_t lo_idx = ((((size_t)(c * 2 + 1) * 3 + tap) * 4 + grp) * 256 + o) * 8 + el;
    wq[hi_idx] = h;
    wq[lo_idx] = l;
}

// ---------------------------------------------------------------------------
// x fp32 -> padded hi/lo bf16 planes [B][TP_][H], data at rows 1..1024.
// ---------------------------------------------------------------------------
__global__ __launch_bounds__(256) void convert_x_kernel(
    const float* __restrict__ x, unsigned short* __restrict__ xh,
    unsigned short* __restrict__ xl)
{
    int gid = blockIdx.x * 256 + threadIdx.x;          // 2,097,152 total
    int b = gid >> 15;
    int rem = gid & 32767;
    int t = rem >> 5;
    int gp = rem & 31;
    const float4* s = (const float4*)(x + ((size_t)b * T_ + t) * H_ + gp * 8);
    float4 a = s[0], c = s[1];
    float vv[8] = {a.x, a.y, a.z, a.w, c.x, c.y, c.z, c.w};
    short8v hv, lv;
    #pragma unroll
    for (int j = 0; j < 8; ++j) {
        unsigned short h = f2bf_rne(vv[j]);
        hv[j] = (short)h;
        lv[j] = (short)f2bf_rne(vv[j] - bf2f(h));
    }
    size_t d = ((size_t)b * TP_ + t + 1) * H_ + gp * 8;
    *(short8v*)(xh + d) = hv;
    *(short8v*)(xl + d) = lv;
}

// ---------------------------------------------------------------------------
// Zero the pad rows (0 and 1025..1055) of all four padded planes.
// ---------------------------------------------------------------------------
__global__ __launch_bounds__(256) void zero_pads_kernel(
    unsigned short* p0, unsigned short* p1, unsigned short* p2, unsigned short* p3)
{
    int gid = blockIdx.x * 256 + threadIdx.x;          // 262,144 total
    unsigned short* planes[4] = {p0, p1, p2, p3};
    int pl = gid >> 16;
    int rem = gid & 65535;
    int b = rem >> 10;
    int rr = (rem >> 5) & 31;
    int gp = rem & 31;
    int row = (rr == 0) ? 0 : (1024 + rr);
    short8v z = {0, 0, 0, 0, 0, 0, 0, 0};
    *(short8v*)(planes[pl] + ((size_t)b * TP_ + row) * H_ + gp * 8) = z;
}

// ---------------------------------------------------------------------------
__global__ __launch_bounds__(256) void init_ld_kernel(float* __restrict__ ld,
                                                      const float* __restrict__ pb) {
    int i = blockIdx.x * 256 + threadIdx.x;
    if (i < B_ * T_) ld[i] = pb[0];
}

// ---------------------------------------------------------------------------
// Conv1d(K=3,SAME)+bias+ReLU, split bf16 MFMA (hh+hl+lh).
// Block 128t x 128oc, 4 waves (2x2), wave tile 64x64, ic chunks of 32.
// X: padded hi/lo planes staged by pure global_load_lds (5 instr/wave/chunk,
//    issued at chunk top -> drained ~free at the chunk barrier). LDS linear
//    [plane][row][64B], A-frag b128 reads bank-uniform.
// W: limb layout -> per-lane direct global->VGPR fragments (L2-resident).
// Per chunk: 3 tap-phases {8 W loads, 8 A ds_reads, 48 MFMA in setprio}.
// MODE 0: LDS-transpose epilogue -> padded hi/lo planes (coalesced b128).
// MODE 1: fused projection epilogue (logdur += relu(v)*pw, wave-reduce+atomic).
// ---------------------------------------------------------------------------
template <int MODE>
__global__ __launch_bounds__(256, 3) void conv_mfma_kernel(
    const unsigned short* __restrict__ xh, const unsigned short* __restrict__ xl,
    const unsigned short* __restrict__ wq,
    const float* __restrict__ bias, const float* __restrict__ pw,
    unsigned short* __restrict__ oh, unsigned short* __restrict__ olo,
    float* __restrict__ logdur)
{
    __shared__ __align__(16) char lds[40960];   // 2 bufs x (2 planes x 160 rows x 64B)

    const int tid = threadIdx.x;
    const int t0 = blockIdx.x * 128;
    const int o0 = blockIdx.y * 128;
    const int b  = blockIdx.z;
    const int lane = tid & 63;
    const int wave = tid >> 6;
    const int r = lane & 15, g = lane >> 4;
    const int wm = wave >> 1, wn = wave & 1;

    // staging role: plane = wm (0->hi, 1->lo), row-half = wn
    const unsigned short* splane = (wm == 0) ? xh : xl;
    const size_t srow0 = (size_t)b * TP_ + t0 + wn * 80;
    const int lrow = lane >> 2, lgrp = lane & 3;

    const unsigned short* wb = wq + (size_t)g * 2048 + (size_t)(o0 + wn * 64 + r) * 8;

    floatx4 acc[4][4];
    #pragma unroll
    for (int fn = 0; fn < 4; ++fn) {
        float bv = bias[o0 + wn * 64 + fn * 16 + r];
        #pragma unroll
        for (int fm = 0; fm < 4; ++fm)
            acc[fm][fn] = (floatx4){bv, bv, bv, bv};
    }

    #define STAGE(c)                                                             \
        {                                                                        \
            const unsigned short* sb = splane + srow0 * H_ + (c) * 32 + lgrp * 8 \
                                       + (size_t)lrow * H_;                      \
            char* db = lds + ((c) & 1) * 20480 + wm * 10240 + wn * 80 * 64;      \
            _Pragma("unroll")                                                    \
            for (int i = 0; i < 5; ++i)                                          \
                gload_lds16(sb + (size_t)i * 16 * H_, db + i * 1024);            \
        }

    STAGE(0);
    __syncthreads();

    #pragma unroll 2
    for (int c = 0; c < 8; ++c) {
        if (c < 7) STAGE(c + 1);

        const char* Xb = lds + (c & 1) * 20480;
        const unsigned short* wc = wb + (size_t)c * 49152;
        #pragma unroll
        for (int tap = 0; tap < 3; ++tap) {
            short8v aH[4], aL[4], bH[4], bL[4];
            #pragma unroll
            for (int fn = 0; fn < 4; ++fn) {
                bH[fn] = *(const short8v*)(wc + (size_t)tap * 8192 + fn * 128);
                bL[fn] = *(const short8v*)(wc + 24576 + (size_t)tap * 8192 + fn * 128);
            }
            #pragma unroll
            for (int fm = 0; fm < 4; ++fm) {
                int off = (wm * 64 + fm * 16 + r + tap) * 64 + g * 16;
                aH[fm] = *(const short8v*)(Xb + off);
                aL[fm] = *(const short8v*)(Xb + 10240 + off);
            }
            __builtin_amdgcn_s_setprio(1);
            #pragma unroll
            for (int fm = 0; fm < 4; ++fm)
                #pragma unroll
                for (int fn = 0; fn < 4; ++fn) {
                    acc[fm][fn] = __builtin_amdgcn_mfma_f32_16x16x32_bf16(
                        aH[fm], bH[fn], acc[fm][fn], 0, 0, 0);
                    acc[fm][fn] = __builtin_amdgcn_mfma_f32_16x16x32_bf16(
                        aH[fm], bL[fn], acc[fm][fn], 0, 0, 0);
                    acc[fm][fn] = __builtin_amdgcn_mfma_f32_16x16x32_bf16(
                        aL[fm], bH[fn], acc[fm][fn], 0, 0, 0);
                }
            __builtin_amdgcn_s_setprio(0);
        }
        __syncthreads();
    }
    #undef STAGE

    if constexpr (MODE == 0) {
        // LDS-transpose epilogue: Ltmp[tau 32][132 u32 pad], 4 passes over fm.
        unsigned int* Ltmp = (unsigned int*)lds;
        #pragma unroll 1
        for (int fm = 0; fm < 4; ++fm) {
            __syncthreads();
            #pragma unroll
            for (int fn = 0; fn < 4; ++fn) {
                int ol = wn * 64 + fn * 16 + r;
                unsigned int* wbase = Ltmp + (wm * 16 + g * 4) * 132 + ol;
                #pragma unroll
                for (int reg = 0; reg < 4; ++reg)
                    wbase[reg * 132] = packhl(fmaxf(acc[fm][fn][reg], 0.f));
            }
            __syncthreads();
            int tau = tid >> 3;
            int c2 = tid & 7;
            int gt = t0 + (tau >> 4) * 64 + fm * 16 + (tau & 15) + 1; // padded row
            size_t dbase = ((size_t)b * TP_ + gt) * H_ + o0;
            #pragma unroll
            for (int half = 0; half < 2; ++half) {
                int oc = c2 * 16 + half * 8;
                uint4 q0 = *(const uint4*)(Ltmp + tau * 132 + oc);
                uint4 q1 = *(const uint4*)(Ltmp + tau * 132 + oc + 4);
                unsigned int uu[8] = {q0.x, q0.y, q0.z, q0.w, q1.x, q1.y, q1.z, q1.w};
                short8v hv, lv;
                #pragma unroll
                for (int j = 0; j < 8; ++j) {
                    hv[j] = (short)(uu[j] & 0xffffu);
                    lv[j] = (short)(uu[j] >> 16);
                }
                *(short8v*)(oh + dbase + oc) = hv;
                *(short8v*)(olo + dbase + oc) = lv;
            }
        }
    } else {
        float pwv[4];
        #pragma unroll
        for (int fn = 0; fn < 4; ++fn) pwv[fn] = pw[o0 + wn * 64 + fn * 16 + r];
        #pragma unroll
        for (int fm = 0; fm < 4; ++fm) {
            #pragma unroll
            for (int reg = 0; reg < 4; ++reg) {
                float s = 0.f;
                #pragma unroll
                for (int fn = 0; fn < 4; ++fn)
                    s += fmaxf(acc[fm][fn][reg], 0.f) * pwv[fn];
                s += __shfl_xor(s, 1, 64);
                s += __shfl_xor(s, 2, 64);
                s += __shfl_xor(s, 4, 64);
                s += __shfl_xor(s, 8, 64);
                if (r == 0)
                    atomicAdd(&logdur[(size_t)b * T_ + t0 + wm * 64 + fm * 16 + g * 4 + reg], s);
            }
        }
    }
}

// ---------------------------------------------------------------------------
// Length regulator (verified R1-R5).
// ---------------------------------------------------------------------------
__global__ __launch_bounds__(256) void regulator_kernel(
    const float* __restrict__ x, const int* __restrict__ dur,
    float* __restrict__ out)
{
    const int b  = blockIdx.y;
    const int r0 = blockIdx.x * 128;
    const int tid = threadIdx.x;
    const int lane = tid & 63;
    const int wv = tid >> 6;

    __shared__ int cum[T_];
    __shared__ int wtot[4];
    __shared__ int sidx[128];

    const int* drow = dur + (size_t)b * T_;
    int base = tid * 4;
    int d0 = drow[base + 0], d1 = drow[base + 1], d2 = drow[base + 2], d3 = drow[base + 3];
    int i0 = d0, i1 = i0 + d1, i2 = i1 + d2, i3 = i2 + d3;
    int lt = i3;
    int v = lt;
    #pragma unroll
    for (int delta = 1; delta < 64; delta <<= 1) {
        int u = __shfl_up(v, delta, 64);
        if (lane >= delta) v += u;
    }
    if (lane == 63) wtot[wv] = v;
    __syncthreads();
    int woff = 0;
    #pragma unroll
    for (int i = 0; i < 4; ++i)
        if (i < wv) woff += wtot[i];
    int excl = woff + v - lt;
    cum[base + 0] = excl + i0;
    cum[base + 1] = excl + i1;
    cum[base + 2] = excl + i2;
    cum[base + 3] = excl + i3;
    __syncthreads();

    int tot = cum[T_ - 1];
    if (tid < 128) {
        int p = r0 + tid;
        int lo = 0, hi = T_;
        while (lo < hi) {
            int mid = (lo + hi) >> 1;
            if (cum[mid] <= p) lo = mid + 1; else hi = mid;
        }
        int idx = lo > (T_ - 1) ? (T_ - 1) : lo;
        sidx[tid] = (p < tot) ? idx : -1;
    }
    __syncthreads();

    const float4* x4 = (const float4*)(x + (size_t)b * T_ * H_);
    float4* o4 = (float4*)(out + ((size_t)b * OUT_LEN_ + r0) * H_);
    for (int rr = 0; rr < 128; rr += 4) {
        int rw = rr + wv;
        int idx = sidx[rw];
        float4 val;
        if (idx >= 0) val = x4[(size_t)idx * (H_ / 4) + lane];
        else          val = make_float4(0.f, 0.f, 0.f, 0.f);
        o4[(size_t)rw * (H_ / 4) + lane] = val;
    }
}

// ---------------------------------------------------------------------------
extern "C" void kernel_launch(void* const* d_in, const int* in_sizes, int n_in,
                              void* d_out, int out_size, void* d_ws, size_t ws_size,
                              hipStream_t stream) {
    const float* x   = (const float*)d_in[0];
    const int*   dur = (const int*)d_in[1];
    const float* w1  = (const float*)d_in[2];
    const float* b1  = (const float*)d_in[3];
    const float* w2  = (const float*)d_in[4];
    const float* b2  = (const float*)d_in[5];
    const float* pw  = (const float*)d_in[6];
    const float* pb  = (const float*)d_in[7];

    float* out = (float*)d_out;
    char*  p   = (char*)d_out;

    // Scratch inside d_out (201.3 MB usable; scratch dead before regulator).
    unsigned short* xph  = (unsigned short*)(p);                  // 34.6 MB
    unsigned short* xpl  = (unsigned short*)(p + 34603008u);      // 34.6 MB
    unsigned short* h1h  = (unsigned short*)(p + 69206016u);      // 34.6 MB
    unsigned short* h1l  = (unsigned short*)(p + 103809024u);     // 34.6 MB
    unsigned short* wq1  = (unsigned short*)(p + 138412032u);     // 786 KB
    unsigned short* wq2  = (unsigned short*)(p + 139198464u);     // 786 KB
    float* logdur = out + (size_t)B_ * OUT_LEN_ * H_;

    convert_w_kernel<<<768, 256, 0, stream>>>(w1, wq1);
    convert_w_kernel<<<768, 256, 0, stream>>>(w2, wq2);
    zero_pads_kernel<<<1024, 256, 0, stream>>>(xph, xpl, h1h, h1l);
    convert_x_kernel<<<8192, 256, 0, stream>>>(x, xph, xpl);
    init_ld_kernel<<<(B_ * T_) / 256, 256, 0, stream>>>(logdur, pb);

    dim3 cgrid(T_ / 128, H_ / 128, B_);
    conv_mfma_kernel<0><<<cgrid, 256, 0, stream>>>(
        xph, xpl, wq1, b1, nullptr, h1h, h1l, nullptr);
    conv_mfma_kernel<1><<<cgrid, 256, 0, stream>>>(
        h1h, h1l, wq2, b2, pw, nullptr, nullptr, logdur);

    regulator_kernel<<<dim3(OUT_LEN_ / 128, B_), 256, 0, stream>>>(x, dur, out);
}

// Round 7
// 415.332 us; speedup vs baseline: 1.2115x; 1.2115x over previous
//
#include <hip/hip_runtime.h>
#include <hip/hip_bf16.h>

#define B_  64
#define T_  1024
#define H_  256
#define OUT_LEN_ 3072
#define TP_ 1056          // padded rows: 1 + 1024 + 31

typedef __attribute__((ext_vector_type(8))) short short8v;
typedef __attribute__((ext_vector_type(4))) float floatx4;

__device__ __forceinline__ unsigned short f2bf_rne(float f) {
    unsigned int u = __float_as_uint(f);
    u += 0x7FFFu + ((u >> 16) & 1u);
    return (unsigned short)(u >> 16);
}
__device__ __forceinline__ float bf2f(unsigned short h) {
    return __uint_as_float(((unsigned int)h) << 16);
}
__device__ __forceinline__ unsigned int packhl(float v) {
    unsigned short h = f2bf_rne(v);
    unsigned short l = f2bf_rne(v - bf2f(h));
    return (unsigned int)h | ((unsigned int)l << 16);
}
__device__ __forceinline__ void gload_lds16(const void* g, void* l) {
    __builtin_amdgcn_global_load_lds(
        (const __attribute__((address_space(1))) unsigned int*)g,
        (__attribute__((address_space(3))) unsigned int*)l, 16, 0, 0);
}

// Plane swizzle: 16B-group slot s holds channel-group s ^ ((padded_row>>1)&3).
// Involution within each 64B 4-group cluster; makes the conv A-frag
// ds_read_b128 pattern hit all 8 bank-groups (2-way = free) while the
// global_load_lds staging stays linear (rule #21: swizzle source + read).

// ---------------------------------------------------------------------------
// w[O][I][3] -> limb layout (unchanged from R4-R6):
// idx = ((((c*2+arr)*3+tap)*4+grp)*256 + o)*8 + el,  ic = c*32+grp*8+el
// ---------------------------------------------------------------------------
__global__ __launch_bounds__(256) void convert_w_kernel(
    const float* __restrict__ w, unsigned short* __restrict__ wq)
{
    int e = blockIdx.x * 256 + threadIdx.x;
    if (e >= H_ * H_ * 3) return;
    int o = e / (H_ * 3);
    int rem = e - o * (H_ * 3);
    int ic = rem / 3;
    int tap = rem - ic * 3;
    float v = w[e];
    unsigned short h = f2bf_rne(v);
    unsigned short l = f2bf_rne(v - bf2f(h));
    int c = ic >> 5, grp = (ic >> 3) & 3, el = ic & 7;
    size_t hi_idx = ((((size_t)(c * 2 + 0) * 3 + tap) * 4 + grp) * 256 + o) * 8 + el;
    size_t lo_idx = ((((size_t)(c * 2 + 1) * 3 + tap) * 4 + grp) * 256 + o) * 8 + el;
    wq[hi_idx] = h;
    wq[lo_idx] = l;
}

// ---------------------------------------------------------------------------
// x fp32 -> padded hi/lo bf16 planes [B][TP_][H], data rows 1..1024,
// channel-group slots pre-swizzled: slot = gp ^ ((row>>1)&3).
// ---------------------------------------------------------------------------
__global__ __launch_bounds__(256) void convert_x_kernel(
    const float* __restrict__ x, unsigned short* __restrict__ xh,
    unsigned short* __restrict__ xl)
{
    int gid = blockIdx.x * 256 + threadIdx.x;          // 2,097,152 total
    int b = gid >> 15;
    int rem = gid & 32767;
    int t = rem >> 5;
    int gp = rem & 31;
    const float4* s = (const float4*)(x + ((size_t)b * T_ + t) * H_ + gp * 8);
    float4 a = s[0], c = s[1];
    float vv[8] = {a.x, a.y, a.z, a.w, c.x, c.y, c.z, c.w};
    short8v hv, lv;
    #pragma unroll
    for (int j = 0; j < 8; ++j) {
        unsigned short h = f2bf_rne(vv[j]);
        hv[j] = (short)h;
        lv[j] = (short)f2bf_rne(vv[j] - bf2f(h));
    }
    int prow = t + 1;
    int slot = gp ^ ((prow >> 1) & 3);
    size_t d = ((size_t)b * TP_ + prow) * H_ + slot * 8;
    *(short8v*)(xh + d) = hv;
    *(short8v*)(xl + d) = lv;
}

// ---------------------------------------------------------------------------
// Zero pad rows (0 and 1025..1055) of all four planes (zeros: swizzle-inv).
// ---------------------------------------------------------------------------
__global__ __launch_bounds__(256) void zero_pads_kernel(
    unsigned short* p0, unsigned short* p1, unsigned short* p2, unsigned short* p3)
{
    int gid = blockIdx.x * 256 + threadIdx.x;          // 262,144 total
    unsigned short* planes[4] = {p0, p1, p2, p3};
    int pl = gid >> 16;
    int rem = gid & 65535;
    int b = rem >> 10;
    int rr = (rem >> 5) & 31;
    int gp = rem & 31;
    int row = (rr == 0) ? 0 : (1024 + rr);
    short8v z = {0, 0, 0, 0, 0, 0, 0, 0};
    *(short8v*)(planes[pl] + ((size_t)b * TP_ + row) * H_ + gp * 8) = z;
}

// ---------------------------------------------------------------------------
__global__ __launch_bounds__(256) void init_ld_kernel(float* __restrict__ ld,
                                                      const float* __restrict__ pb) {
    int i = blockIdx.x * 256 + threadIdx.x;
    if (i < B_ * T_) ld[i] = pb[0];
}

// ---------------------------------------------------------------------------
// Conv1d(K=3,SAME)+bias+ReLU, split bf16 MFMA (hh+hl+lh).
// Block 128t x 128oc, 4 waves (2x2), wave tile 64x64, ic chunks of 32.
// X: pre-swizzled padded hi/lo planes staged via pure global_load_lds
//    (5 instr/wave/chunk); A-frag reads apply the same slot XOR ->
//    all 8 bank-groups covered, 2-way = conflict-free.
// W: limb layout -> per-lane direct global->VGPR fragments (L2-resident).
// Per chunk: 3 tap-phases {8 W loads, 8 A ds_reads, 48 MFMA in setprio}.
// MODE 0: 2-pass LDS-transpose epilogue -> pre-swizzled hi/lo planes.
// MODE 1: fused projection epilogue (logdur += relu(v)*pw).
// ---------------------------------------------------------------------------
template <int MODE>
__global__ __launch_bounds__(256, 3) void conv_mfma_kernel(
    const unsigned short* __restrict__ xh, const unsigned short* __restrict__ xl,
    const unsigned short* __restrict__ wq,
    const float* __restrict__ bias, const float* __restrict__ pw,
    unsigned short* __restrict__ oh, unsigned short* __restrict__ olo,
    float* __restrict__ logdur)
{
    __shared__ __align__(16) char lds[40960];   // 2 bufs x (2 planes x 160 rows x 64B)

    const int tid = threadIdx.x;
    const int t0 = blockIdx.x * 128;
    const int o0 = blockIdx.y * 128;
    const int b  = blockIdx.z;
    const int lane = tid & 63;
    const int wave = tid >> 6;
    const int r = lane & 15, g = lane >> 4;
    const int wm = wave >> 1, wn = wave & 1;

    // staging role: plane = wm (0->hi, 1->lo), row-half = wn
    const unsigned short* splane = (wm == 0) ? xh : xl;
    const size_t srow0 = (size_t)b * TP_ + t0 + wn * 80;
    const int lrow = lane >> 2, lgrp = lane & 3;

    const unsigned short* wb = wq + (size_t)g * 2048 + (size_t)(o0 + wn * 64 + r) * 8;

    floatx4 acc[4][4];
    #pragma unroll
    for (int fn = 0; fn < 4; ++fn) {
        float bv = bias[o0 + wn * 64 + fn * 16 + r];
        #pragma unroll
        for (int fm = 0; fm < 4; ++fm)
            acc[fm][fn] = (floatx4){bv, bv, bv, bv};
    }

    #define STAGE(c)                                                             \
        {                                                                        \
            const unsigned short* sb = splane + srow0 * H_ + (c) * 32 + lgrp * 8 \
                                       + (size_t)lrow * H_;                      \
            char* db = lds + ((c) & 1) * 20480 + wm * 10240 + wn * 80 * 64;      \
            _Pragma("unroll")                                                    \
            for (int i = 0; i < 5; ++i)                                          \
                gload_lds16(sb + (size_t)i * 16 * H_, db + i * 1024);            \
        }

    STAGE(0);
    __syncthreads();

    #pragma unroll 2
    for (int c = 0; c < 8; ++c) {
        if (c < 7) STAGE(c + 1);

        const char* Xb = lds + (c & 1) * 20480;
        const unsigned short* wc = wb + (size_t)c * 49152;
        #pragma unroll
        for (int tap = 0; tap < 3; ++tap) {
            short8v aH[4], aL[4], bH[4], bL[4];
            #pragma unroll
            for (int fn = 0; fn < 4; ++fn) {
                bH[fn] = *(const short8v*)(wc + (size_t)tap * 8192 + fn * 128);
                bL[fn] = *(const short8v*)(wc + 24576 + (size_t)tap * 8192 + fn * 128);
            }
            #pragma unroll
            for (int fm = 0; fm < 4; ++fm) {
                int row = wm * 64 + fm * 16 + r + tap;
                int off = row * 64 + ((g ^ ((row >> 1) & 3)) << 4);
                aH[fm] = *(const short8v*)(Xb + off);
                aL[fm] = *(const short8v*)(Xb + 10240 + off);
            }
            __builtin_amdgcn_s_setprio(1);
            #pragma unroll
            for (int fm = 0; fm < 4; ++fm)
                #pragma unroll
                for (int fn = 0; fn < 4; ++fn) {
                    acc[fm][fn] = __builtin_amdgcn_mfma_f32_16x16x32_bf16(
                        aH[fm], bH[fn], acc[fm][fn], 0, 0, 0);
                    acc[fm][fn] = __builtin_amdgcn_mfma_f32_16x16x32_bf16(
                        aH[fm], bL[fn], acc[fm][fn], 0, 0, 0);
                    acc[fm][fn] = __builtin_amdgcn_mfma_f32_16x16x32_bf16(
                        aL[fm], bH[fn], acc[fm][fn], 0, 0, 0);
                }
            __builtin_amdgcn_s_setprio(0);
        }
        __syncthreads();
    }
    #undef STAGE

    if constexpr (MODE == 0) {
        // 2-pass LDS-transpose epilogue: Ltmp[64 rows][132 u32 pad] = 33.8 KB.
        // Pass p covers fm = {2p, 2p+1}; writes go to pre-swizzled plane slots.
        unsigned int* Ltmp = (unsigned int*)lds;
        #pragma unroll
        for (int p = 0; p < 2; ++p) {
            __syncthreads();
            #pragma unroll
            for (int sub = 0; sub < 2; ++sub) {
                #pragma unroll
                for (int fn = 0; fn < 4; ++fn) {
                    int ol = wn * 64 + fn * 16 + r;
                    unsigned int* wbase =
                        Ltmp + (sub * 32 + wm * 16 + g * 4) * 132 + ol;
                    #pragma unroll
                    for (int reg = 0; reg < 4; ++reg)
                        wbase[reg * 132] =
                            packhl(fmaxf(acc[p * 2 + sub][fn][reg], 0.f));
                }
            }
            __syncthreads();
            int tau6 = tid >> 2;           // 0..63
            int c4 = tid & 3;
            int sub = tau6 >> 5;
            int wmr = (tau6 >> 4) & 1;
            int t15 = tau6 & 15;
            int gt = t0 + wmr * 64 + (p * 2 + sub) * 16 + t15 + 1;  // padded row
            int k = (gt >> 1) & 3;
            size_t dbase = ((size_t)b * TP_ + gt) * H_ + o0;
            const unsigned int* rbase = Ltmp + (sub * 32 + wmr * 16 + t15) * 132;
            #pragma unroll
            for (int q = 0; q < 4; ++q) {
                int j = c4 + q * 4;        // group position within block, 0..15
                uint4 q0 = *(const uint4*)(rbase + j * 8);
                uint4 q1 = *(const uint4*)(rbase + j * 8 + 4);
                unsigned int uu[8] = {q0.x, q0.y, q0.z, q0.w,
                                      q1.x, q1.y, q1.z, q1.w};
                short8v hv, lv;
                #pragma unroll
                for (int e = 0; e < 8; ++e) {
                    hv[e] = (short)(uu[e] & 0xffffu);
                    lv[e] = (short)(uu[e] >> 16);
                }
                int slot = j ^ k;
                *(short8v*)(oh + dbase + slot * 8) = hv;
                *(short8v*)(olo + dbase + slot * 8) = lv;
            }
        }
    } else {
        float pwv[4];
        #pragma unroll
        for (int fn = 0; fn < 4; ++fn) pwv[fn] = pw[o0 + wn * 64 + fn * 16 + r];
        #pragma unroll
        for (int fm = 0; fm < 4; ++fm) {
            #pragma unroll
            for (int reg = 0; reg < 4; ++reg) {
                float s = 0.f;
                #pragma unroll
                for (int fn = 0; fn < 4; ++fn)
                    s += fmaxf(acc[fm][fn][reg], 0.f) * pwv[fn];
                s += __shfl_xor(s, 1, 64);
                s += __shfl_xor(s, 2, 64);
                s += __shfl_xor(s, 4, 64);
                s += __shfl_xor(s, 8, 64);
                if (r == 0)
                    atomicAdd(&logdur[(size_t)b * T_ + t0 + wm * 64 + fm * 16 + g * 4 + reg], s);
            }
        }
    }
}

// ---------------------------------------------------------------------------
// Length regulator (verified R1-R6).
// ---------------------------------------------------------------------------
__global__ __launch_bounds__(256) void regulator_kernel(
    const float* __restrict__ x, const int* __restrict__ dur,
    float* __restrict__ out)
{
    const int b  = blockIdx.y;
    const int r0 = blockIdx.x * 128;
    const int tid = threadIdx.x;
    const int lane = tid & 63;
    const int wv = tid >> 6;

    __shared__ int cum[T_];
    __shared__ int wtot[4];
    __shared__ int sidx[128];

    const int* drow = dur + (size_t)b * T_;
    int base = tid * 4;
    int d0 = drow[base + 0], d1 = drow[base + 1], d2 = drow[base + 2], d3 = drow[base + 3];
    int i0 = d0, i1 = i0 + d1, i2 = i1 + d2, i3 = i2 + d3;
    int lt = i3;
    int v = lt;
    #pragma unroll
    for (int delta = 1; delta < 64; delta <<= 1) {
        int u = __shfl_up(v, delta, 64);
        if (lane >= delta) v += u;
    }
    if (lane == 63) wtot[wv] = v;
    __syncthreads();
    int woff = 0;
    #pragma unroll
    for (int i = 0; i < 4; ++i)
        if (i < wv) woff += wtot[i];
    int excl = woff + v - lt;
    cum[base + 0] = excl + i0;
    cum[base + 1] = excl + i1;
    cum[base + 2] = excl + i2;
    cum[base + 3] = excl + i3;
    __syncthreads();

    int tot = cum[T_ - 1];
    if (tid < 128) {
        int p = r0 + tid;
        int lo = 0, hi = T_;
        while (lo < hi) {
            int mid = (lo + hi) >> 1;
            if (cum[mid] <= p) lo = mid + 1; else hi = mid;
        }
        int idx = lo > (T_ - 1) ? (T_ - 1) : lo;
        sidx[tid] = (p < tot) ? idx : -1;
    }
    __syncthreads();

    const float4* x4 = (const float4*)(x + (size_t)b * T_ * H_);
    float4* o4 = (float4*)(out + ((size_t)b * OUT_LEN_ + r0) * H_);
    for (int rr = 0; rr < 128; rr += 4) {
        int rw = rr + wv;
        int idx = sidx[rw];
        float4 val;
        if (idx >= 0) val = x4[(size_t)idx * (H_ / 4) + lane];
        else          val = make_float4(0.f, 0.f, 0.f, 0.f);
        o4[(size_t)rw * (H_ / 4) + lane] = val;
    }
}

// ---------------------------------------------------------------------------
extern "C" void kernel_launch(void* const* d_in, const int* in_sizes, int n_in,
                              void* d_out, int out_size, void* d_ws, size_t ws_size,
                              hipStream_t stream) {
    const float* x   = (const float*)d_in[0];
    const int*   dur = (const int*)d_in[1];
    const float* w1  = (const float*)d_in[2];
    const float* b1  = (const float*)d_in[3];
    const float* w2  = (const float*)d_in[4];
    const float* b2  = (const float*)d_in[5];
    const float* pw  = (const float*)d_in[6];
    const float* pb  = (const float*)d_in[7];

    float* out = (float*)d_out;
    char*  p   = (char*)d_out;

    // Scratch inside d_out (201.3 MB usable; scratch dead before regulator).
    unsigned short* xph  = (unsigned short*)(p);                  // 34.6 MB
    unsigned short* xpl  = (unsigned short*)(p + 34603008u);      // 34.6 MB
    unsigned short* h1h  = (unsigned short*)(p + 69206016u);      // 34.6 MB
    unsigned short* h1l  = (unsigned short*)(p + 103809024u);     // 34.6 MB
    unsigned short* wq1  = (unsigned short*)(p + 138412032u);     // 786 KB
    unsigned short* wq2  = (unsigned short*)(p + 139198464u);     // 786 KB
    float* logdur = out + (size_t)B_ * OUT_LEN_ * H_;

    convert_w_kernel<<<768, 256, 0, stream>>>(w1, wq1);
    convert_w_kernel<<<768, 256, 0, stream>>>(w2, wq2);
    zero_pads_kernel<<<1024, 256, 0, stream>>>(xph, xpl, h1h, h1l);
    convert_x_kernel<<<8192, 256, 0, stream>>>(x, xph, xpl);
    init_ld_kernel<<<(B_ * T_) / 256, 256, 0, stream>>>(logdur, pb);

    dim3 cgrid(T_ / 128, H_ / 128, B_);
    conv_mfma_kernel<0><<<cgrid, 256, 0, stream>>>(
        xph, xpl, wq1, b1, nullptr, h1h, h1l, nullptr);
    conv_mfma_kernel<1><<<cgrid, 256, 0, stream>>>(
        h1h, h1l, wq2, b2, pw, nullptr, nullptr, logdur);

    regulator_kernel<<<dim3(OUT_LEN_ / 128, B_), 256, 0, stream>>>(x, dur, out);
}

// Round 8
// 376.574 us; speedup vs baseline: 1.3362x; 1.1029x over previous
//
#include <hip/hip_runtime.h>
#include <hip/hip_bf16.h>

#define B_  64
#define T_  1024
#define H_  256
#define OUT_LEN_ 3072

typedef __attribute__((ext_vector_type(8))) short short8v;
typedef __attribute__((ext_vector_type(4))) float floatx4;

__device__ __forceinline__ unsigned short f2bf_rne(float f) {
    unsigned int u = __float_as_uint(f);
    u += 0x7FFFu + ((u >> 16) & 1u);
    return (unsigned short)(u >> 16);
}
__device__ __forceinline__ float bf2f(unsigned short h) {
    return __uint_as_float(((unsigned int)h) << 16);
}

// ---------------------------------------------------------------------------
// w[O][I][3] -> limb layout (unchanged from R4-R7):
// idx = ((((c*2+arr)*3+tap)*4+grp)*256 + o)*8 + el,  ic = c*32+grp*8+el
// ---------------------------------------------------------------------------
__global__ __launch_bounds__(256) void convert_w_kernel(
    const float* __restrict__ w, unsigned short* __restrict__ wq)
{
    int e = blockIdx.x * 256 + threadIdx.x;
    if (e >= H_ * H_ * 3) return;
    int o = e / (H_ * 3);
    int rem = e - o * (H_ * 3);
    int ic = rem / 3;
    int tap = rem - ic * 3;
    float v = w[e];
    unsigned short h = f2bf_rne(v);
    unsigned short l = f2bf_rne(v - bf2f(h));
    int c = ic >> 5, grp = (ic >> 3) & 3, el = ic & 7;
    size_t hi_idx = ((((size_t)(c * 2 + 0) * 3 + tap) * 4 + grp) * 256 + o) * 8 + el;
    size_t lo_idx = ((((size_t)(c * 2 + 1) * 3 + tap) * 4 + grp) * 256 + o) * 8 + el;
    wq[hi_idx] = h;
    wq[lo_idx] = l;
}

// ---------------------------------------------------------------------------
__global__ __launch_bounds__(256) void init_ld_kernel(float* __restrict__ ld,
                                                      const float* __restrict__ pb) {
    int i = blockIdx.x * 256 + threadIdx.x;
    if (i < B_ * T_) ld[i] = pb[0];
}

// ---------------------------------------------------------------------------
// Conv1d(K=3, SAME) + bias + ReLU, split-precision bf16 MFMA (hh+hl+lh).
// Block 128t x 128oc, 4 waves (2x2), wave tile 64x64 (4x4 frags 16x16x32),
// ic chunks of 32, pipelined:
//   per chunk c: hoist ALL 24 W fragment loads (global->VGPR, L2) |
//   issue X loads(c+1) | per-tap {8 A ds_reads + 48 MFMA in setprio} |
//   convert+ds_write Xs[(c+1)&1] | ONE barrier.
// The W hoist is the R8 fix: R4-R7 reloaded W inside the tap loop (VGPR=72
// allocation), serializing L2-latency -> MFMA every tap.
// X LDS double-buffered, rows 80B padded (bank period 8 -> b128 2-way free).
// MODE 0: in fp32 x, out packed u32 (bf16 hi | lo<<16).
// MODE 1: in packed u32, epilogue fuses projection (logdur += relu(v)*pw).
// ---------------------------------------------------------------------------
template <int MODE>
__global__ __launch_bounds__(256, 2) void conv_mfma_kernel(
    const float* __restrict__ xin,          // MODE 0
    const unsigned int* __restrict__ pin,   // MODE 1
    const unsigned short* __restrict__ wq,  // limb layout (see convert_w)
    const float* __restrict__ bias,
    const float* __restrict__ pw,           // MODE 1
    unsigned int* __restrict__ opacked,     // MODE 0
    float* __restrict__ logdur)             // MODE 1
{
    __shared__ __align__(16) char lds[2][20800];   // per buf: XsH 10400 | XsL 10400

    const int tid  = threadIdx.x;
    const int t0   = blockIdx.x * 128;
    const int o0   = blockIdx.y * 128;
    const int b    = blockIdx.z;
    const int lane = tid & 63;
    const int wave = tid >> 6;
    const int r    = lane & 15;       // frag row (A: time) / col (B: oc)
    const int g    = lane >> 4;       // k-group (8 bf16)
    const int wm   = wave >> 1;       // wave row (time)
    const int wn   = wave & 1;        // wave col (oc)

    const size_t abase = (size_t)b * T_ * H_;

    // X staging ownership: it0: (row=tid>>2, grp=tid&3); it1: row+64;
    // it2 (tid<8): rows 128..129.
    const int srow0 = tid >> 2, sgrp = tid & 3;
    const int gt0 = t0 - 1 + srow0;
    const int gt1 = gt0 + 64;
    const int gt2 = t0 - 1 + 128 + (tid >> 2);     // only tid<8
    const bool v0 = (gt0 >= 0) && (gt0 < T_);
    const bool v1 = (gt1 < T_);
    const bool v2 = (tid < 8) && (gt2 < T_);

    // W per-lane fragment base: frag(c,arr,tap,fn) =
    //   wb + (c*24 + arr*12 + tap*4)*2048 + fn*128
    const unsigned short* wb = wq + (size_t)g * 2048 + (size_t)(o0 + wn * 64 + r) * 8;

    floatx4 acc[4][4];
    #pragma unroll
    for (int fn = 0; fn < 4; ++fn) {
        float bv = bias[o0 + wn * 64 + fn * 16 + r];
        #pragma unroll
        for (int fm = 0; fm < 4; ++fm)
            acc[fm][fn] = (floatx4){bv, bv, bv, bv};
    }

    auto stage_commit = [&](int buf, short8v h0, short8v l0, short8v h1,
                            short8v l1, short8v h2, short8v l2) {
        char* XsH = lds[buf];
        char* XsL = lds[buf] + 10400;
        int off0 = srow0 * 80 + sgrp * 16;
        *(short8v*)(XsH + off0) = h0;
        *(short8v*)(XsL + off0) = l0;
        int off1 = off0 + 64 * 80;
        *(short8v*)(XsH + off1) = h1;
        *(short8v*)(XsL + off1) = l1;
        if (tid < 8) {
            int off2 = (128 + (tid >> 2)) * 80 + sgrp * 16;
            *(short8v*)(XsH + off2) = h2;
            *(short8v*)(XsL + off2) = l2;
        }
    };

    #define LOAD_X_F32(gt, valid, ra, rb)                                        \
        if (valid) {                                                             \
            const float4* s = (const float4*)(xin + abase + (size_t)(gt) * H_ +  \
                                              ic_n + sgrp * 8);                  \
            ra = s[0]; rb = s[1];                                                \
        }
    #define LOAD_X_U32(gt, valid, ra, rb)                                        \
        if (valid) {                                                             \
            const uint4* s = (const uint4*)(pin + abase + (size_t)(gt) * H_ +    \
                                            ic_n + sgrp * 8);                    \
            ra = s[0]; rb = s[1];                                                \
        }
    #define CVT_F32(ra, rb, hv, lv)                                              \
        {                                                                        \
            float vv[8] = {ra.x, ra.y, ra.z, ra.w, rb.x, rb.y, rb.z, rb.w};      \
            _Pragma("unroll")                                                    \
            for (int j = 0; j < 8; ++j) {                                        \
                unsigned short h = f2bf_rne(vv[j]);                              \
                hv[j] = (short)h;                                                \
                lv[j] = (short)f2bf_rne(vv[j] - bf2f(h));                        \
            }                                                                    \
        }
    #define CVT_U32(ra, rb, hv, lv)                                              \
        {                                                                        \
            unsigned int uu[8] = {ra.x, ra.y, ra.z, ra.w, rb.x, rb.y, rb.z, rb.w};\
            _Pragma("unroll")                                                    \
            for (int j = 0; j < 8; ++j) {                                        \
                hv[j] = (short)(uu[j] & 0xffffu);                                \
                lv[j] = (short)(uu[j] >> 16);                                    \
            }                                                                    \
        }

    // ---- prologue: stage chunk 0 into buf 0 ----
    {
        const int ic_n = 0;
        float4 fa0{}, fb0{}, fa1{}, fb1{}, fa2{}, fb2{};
        uint4  ua0{}, ub0{}, ua1{}, ub1{}, ua2{}, ub2{};
        if constexpr (MODE == 0) {
            LOAD_X_F32(gt0, v0, fa0, fb0);
            LOAD_X_F32(gt1, v1, fa1, fb1);
            LOAD_X_F32(gt2, v2, fa2, fb2);
        } else {
            LOAD_X_U32(gt0, v0, ua0, ub0);
            LOAD_X_U32(gt1, v1, ua1, ub1);
            LOAD_X_U32(gt2, v2, ua2, ub2);
        }
        short8v h0{}, l0{}, h1{}, l1{}, h2{}, l2{};
        if constexpr (MODE == 0) {
            CVT_F32(fa0, fb0, h0, l0);
            CVT_F32(fa1, fb1, h1, l1);
            CVT_F32(fa2, fb2, h2, l2);
        } else {
            CVT_U32(ua0, ub0, h0, l0);
            CVT_U32(ua1, ub1, h1, l1);
            CVT_U32(ua2, ub2, h2, l2);
        }
        stage_commit(0, h0, l0, h1, l1, h2, l2);
    }
    __syncthreads();

    // ---- main pipeline over 8 ic-chunks ----
    #pragma unroll 2
    for (int c = 0; c < 8; ++c) {
        const int cur = c & 1;
        const bool pf = (c < 7);
        const int ic_n = (c + 1) * 32;

        // (A) hoist ALL 24 W fragment loads for this chunk (issue first so the
        //     MFMA wait is vmcnt(#X) with X prefetch still in flight)
        const unsigned short* wc = wb + (size_t)c * 24 * 2048;
        short8v bH[3][4], bL[3][4];
        #pragma unroll
        for (int tap = 0; tap < 3; ++tap)
            #pragma unroll
            for (int fn = 0; fn < 4; ++fn) {
                bH[tap][fn] = *(const short8v*)(wc + (size_t)tap * 4 * 2048 + fn * 128);
                bL[tap][fn] = *(const short8v*)(wc + (size_t)(12 + tap * 4) * 2048 + fn * 128);
            }

        // (B) issue next-chunk X loads (latency hides under this chunk's MFMAs)
        float4 fa0{}, fb0{}, fa1{}, fb1{}, fa2{}, fb2{};
        uint4  ua0{}, ub0{}, ua1{}, ub1{}, ua2{}, ub2{};
        if (pf) {
            if constexpr (MODE == 0) {
                LOAD_X_F32(gt0, v0, fa0, fb0);
                LOAD_X_F32(gt1, v1, fa1, fb1);
                LOAD_X_F32(gt2, v2, fa2, fb2);
            } else {
                LOAD_X_U32(gt0, v0, ua0, ub0);
                LOAD_X_U32(gt1, v1, ua1, ub1);
                LOAD_X_U32(gt2, v2, ua2, ub2);
            }
        }

        // (C) per-tap: 8 A ds_reads + 48 MFMA (W already in VGPRs)
        const char* XsH = lds[cur];
        const char* XsL = lds[cur] + 10400;
        const int arow = (wm * 64 + r) * 80 + g * 16;
        #pragma unroll
        for (int tap = 0; tap < 3; ++tap) {
            short8v aH[4], aL[4];
            #pragma unroll
            for (int fm = 0; fm < 4; ++fm) {
                int off = arow + (fm * 16 + tap) * 80;
                aH[fm] = *(const short8v*)(XsH + off);
                aL[fm] = *(const short8v*)(XsL + off);
            }
            __builtin_amdgcn_s_setprio(1);
            #pragma unroll
            for (int fm = 0; fm < 4; ++fm)
                #pragma unroll
                for (int fn = 0; fn < 4; ++fn) {
                    acc[fm][fn] = __builtin_amdgcn_mfma_f32_16x16x32_bf16(
                        aH[fm], bH[tap][fn], acc[fm][fn], 0, 0, 0);
                    acc[fm][fn] = __builtin_amdgcn_mfma_f32_16x16x32_bf16(
                        aH[fm], bL[tap][fn], acc[fm][fn], 0, 0, 0);
                    acc[fm][fn] = __builtin_amdgcn_mfma_f32_16x16x32_bf16(
                        aL[fm], bH[tap][fn], acc[fm][fn], 0, 0, 0);
                }
            __builtin_amdgcn_s_setprio(0);
        }

        // (D) convert + commit next-chunk X into the other buffer
        if (pf) {
            short8v h0{}, l0{}, h1{}, l1{}, h2{}, l2{};
            if constexpr (MODE == 0) {
                CVT_F32(fa0, fb0, h0, l0);
                CVT_F32(fa1, fb1, h1, l1);
                CVT_F32(fa2, fb2, h2, l2);
            } else {
                CVT_U32(ua0, ub0, h0, l0);
                CVT_U32(ua1, ub1, h1, l1);
                CVT_U32(ua2, ub2, h2, l2);
            }
            stage_commit(cur ^ 1, h0, l0, h1, l1, h2, l2);
        }
        __syncthreads();
    }

    // ---- epilogue (C/D: col=lane&15 -> oc, row=(lane>>4)*4+reg -> t) ----
    if constexpr (MODE == 0) {
        unsigned int* ob = opacked + abase;
        #pragma unroll
        for (int fm = 0; fm < 4; ++fm) {
            int trow = t0 + wm * 64 + fm * 16 + g * 4;
            #pragma unroll
            for (int fn = 0; fn < 4; ++fn) {
                int o = o0 + wn * 64 + fn * 16 + r;
                #pragma unroll
                for (int reg = 0; reg < 4; ++reg) {
                    float v = fmaxf(acc[fm][fn][reg], 0.f);
                    unsigned short h = f2bf_rne(v);
                    unsigned short l = f2bf_rne(v - bf2f(h));
                    ob[(size_t)(trow + reg) * H_ + o] =
                        (unsigned int)h | ((unsigned int)l << 16);
                }
            }
        }
    } else {
        float pwv[4];
        #pragma unroll
        for (int fn = 0; fn < 4; ++fn) pwv[fn] = pw[o0 + wn * 64 + fn * 16 + r];
        #pragma unroll
        for (int fm = 0; fm < 4; ++fm) {
            #pragma unroll
            for (int reg = 0; reg < 4; ++reg) {
                float s = 0.f;
                #pragma unroll
                for (int fn = 0; fn < 4; ++fn)
                    s += fmaxf(acc[fm][fn][reg], 0.f) * pwv[fn];
                s += __shfl_xor(s, 1, 64);
                s += __shfl_xor(s, 2, 64);
                s += __shfl_xor(s, 4, 64);
                s += __shfl_xor(s, 8, 64);
                if (r == 0)
                    atomicAdd(&logdur[(size_t)b * T_ + t0 + wm * 64 + fm * 16 + g * 4 + reg], s);
            }
        }
    }
}

// ---------------------------------------------------------------------------
// Length regulator (verified R1-R7).
// ---------------------------------------------------------------------------
__global__ __launch_bounds__(256) void regulator_kernel(
    const float* __restrict__ x, const int* __restrict__ dur,
    float* __restrict__ out)
{
    const int b  = blockIdx.y;
    const int r0 = blockIdx.x * 128;
    const int tid = threadIdx.x;
    const int lane = tid & 63;
    const int wv = tid >> 6;

    __shared__ int cum[T_];
    __shared__ int wtot[4];
    __shared__ int sidx[128];

    const int* drow = dur + (size_t)b * T_;
    int base = tid * 4;
    int d0 = drow[base + 0], d1 = drow[base + 1], d2 = drow[base + 2], d3 = drow[base + 3];
    int i0 = d0, i1 = i0 + d1, i2 = i1 + d2, i3 = i2 + d3;
    int lt = i3;
    int v = lt;
    #pragma unroll
    for (int delta = 1; delta < 64; delta <<= 1) {
        int u = __shfl_up(v, delta, 64);
        if (lane >= delta) v += u;
    }
    if (lane == 63) wtot[wv] = v;
    __syncthreads();
    int woff = 0;
    #pragma unroll
    for (int i = 0; i < 4; ++i)
        if (i < wv) woff += wtot[i];
    int excl = woff + v - lt;
    cum[base + 0] = excl + i0;
    cum[base + 1] = excl + i1;
    cum[base + 2] = excl + i2;
    cum[base + 3] = excl + i3;
    __syncthreads();

    int tot = cum[T_ - 1];
    if (tid < 128) {
        int p = r0 + tid;
        int lo = 0, hi = T_;
        while (lo < hi) {
            int mid = (lo + hi) >> 1;
            if (cum[mid] <= p) lo = mid + 1; else hi = mid;
        }
        int idx = lo > (T_ - 1) ? (T_ - 1) : lo;
        sidx[tid] = (p < tot) ? idx : -1;
    }
    __syncthreads();

    const float4* x4 = (const float4*)(x + (size_t)b * T_ * H_);
    float4* o4 = (float4*)(out + ((size_t)b * OUT_LEN_ + r0) * H_);
    for (int rr = 0; rr < 128; rr += 4) {
        int rw = rr + wv;
        int idx = sidx[rw];
        float4 val;
        if (idx >= 0) val = x4[(size_t)idx * (H_ / 4) + lane];
        else          val = make_float4(0.f, 0.f, 0.f, 0.f);
        o4[(size_t)rw * (H_ / 4) + lane] = val;
    }
}

// ---------------------------------------------------------------------------
extern "C" void kernel_launch(void* const* d_in, const int* in_sizes, int n_in,
                              void* d_out, int out_size, void* d_ws, size_t ws_size,
                              hipStream_t stream) {
    const float* x   = (const float*)d_in[0];
    const int*   dur = (const int*)d_in[1];
    const float* w1  = (const float*)d_in[2];
    const float* b1  = (const float*)d_in[3];
    const float* w2  = (const float*)d_in[4];
    const float* b2  = (const float*)d_in[5];
    const float* pw  = (const float*)d_in[6];
    const float* pb  = (const float*)d_in[7];

    float* out = (float*)d_out;                       // [B][OUT_LEN][H] + [B][T]
    char*  p   = (char*)d_out;

    // Scratch inside d_out (201.6 MB). h1p dead once conv2 finishes;
    // regulator overwrites [0, 201.3MB) last.
    unsigned int*   h1p = (unsigned int*)(p);                   // 67.1 MB packed bf16 hi|lo
    unsigned short* wq1 = (unsigned short*)(p + 134217728u);    // 786 KB limb layout
    unsigned short* wq2 = (unsigned short*)(p + 135004160u);    // 786 KB
    float* logdur = out + (size_t)B_ * OUT_LEN_ * H_;           // real output tail

    convert_w_kernel<<<768, 256, 0, stream>>>(w1, wq1);
    convert_w_kernel<<<768, 256, 0, stream>>>(w2, wq2);
    init_ld_kernel<<<(B_ * T_) / 256, 256, 0, stream>>>(logdur, pb);

    dim3 cgrid(T_ / 128, H_ / 128, B_);
    conv_mfma_kernel<0><<<cgrid, 256, 0, stream>>>(
        x, nullptr, wq1, b1, nullptr, h1p, nullptr);
    conv_mfma_kernel<1><<<cgrid, 256, 0, stream>>>(
        nullptr, h1p, wq2, b2, pw, nullptr, logdur);

    regulator_kernel<<<dim3(OUT_LEN_ / 128, B_), 256, 0, stream>>>(x, dur, out);
}